// Round 7
// baseline (283.944 us; speedup 1.0000x reference)
//
#include <hip/hip_runtime.h>
#include <hip/hip_fp16.h>
#include <math.h>

// Problem constants
#define BATCH 256
#define CIN 3
#define HW 128
#define OC 16
#define POOLED 63          // pooled spatial dim
#define FEAT 63504         // OC*63*63
#define NH 256
#define FANIN 512
#define NO 10
#define CHW (CIN*HW*HW)    // 49152

// packed f16 max — ROCm 7.2 lacks __hmax2 on gfx950; pattern-matches to v_pk_max_f16.
__device__ inline __half2 h2max(__half2 a, __half2 b) {
    return __halves2half2(__hmax(__low2half(a),  __low2half(b)),
                          __hmax(__high2half(a), __high2half(b)));
}

// ---- Kernel 1: transpose+convert inputs (B, CHW) fp32 -> (CHW, B) f16 ----------
__global__ __launch_bounds__(256) void transpose_f16_kernel(const float* __restrict__ in,
                                                            __half* __restrict__ outh) {
    __shared__ float tile[64][65];   // tile[b_local][f_local]
    const int f0 = blockIdx.x * 64;
    const int b0 = blockIdx.y * 64;
    const int t  = threadIdx.x;
    // read phase: float4 along f, coalesced
    {
        const int r  = t >> 4;          // 0..15
        const int cg = t & 15;          // 0..15
#pragma unroll
        for (int it = 0; it < 4; ++it) {
            const int bl = r + 16 * it;
            const float4 v = *(const float4*)&in[(size_t)(b0 + bl) * CHW + f0 + cg * 4];
            tile[bl][cg * 4 + 0] = v.x;
            tile[bl][cg * 4 + 1] = v.y;
            tile[bl][cg * 4 + 2] = v.z;
            tile[bl][cg * 4 + 3] = v.w;
        }
    }
    __syncthreads();
    // write phase: pack 8 b's (4 half2) per f row -> 16B store
    {
        const int bg = t & 7;
#pragma unroll
        for (int it = 0; it < 2; ++it) {
            const int fl = (t >> 3) + 32 * it;   // 0..63
            __half2 hv[4];
            hv[0] = __floats2half2_rn(tile[bg * 8 + 0][fl], tile[bg * 8 + 1][fl]);
            hv[1] = __floats2half2_rn(tile[bg * 8 + 2][fl], tile[bg * 8 + 3][fl]);
            hv[2] = __floats2half2_rn(tile[bg * 8 + 4][fl], tile[bg * 8 + 5][fl]);
            hv[3] = __floats2half2_rn(tile[bg * 8 + 6][fl], tile[bg * 8 + 7][fl]);
            *(float4*)&outh[(size_t)(f0 + fl) * BATCH + b0 + bg * 8] = *(float4*)hv;
        }
    }
}

// ---- Kernel 2: conv3x3 + bias + relu + maxpool2x2, packed-f16 ------------------
// inT2: (C,H,W, B/2) half2. featsT2: (FEAT, B/2) half2.
// Block = ONE pooled pixel (i,j), half the batch pairs. 256 thr = 64 bp x 4 oc-grps.
// R6 lesson: 216 scalar ds_read weights + VGPR 136 (3 waves/SIMD) = latency-bound
// (VALUBusy 36%, occ 10.7%). Fix: small live set (~60 regs -> 6-8 waves/SIMD) and
// weights padded 9->12 per (oc,c) so they load as 3x ds_read_b128 broadcasts.
__global__ __launch_bounds__(256, 4) void conv_pool_kernel(const __half2* __restrict__ inT2,
                                                           const float* __restrict__ cw,
                                                           const float* __restrict__ cb,
                                                           __half2* __restrict__ featsT2) {
    __shared__ __half2 swb[OC][CIN][12];   // padded, 16B-aligned rows
    __shared__ __half2 sbias[OC];
    const int t = threadIdx.x;
    for (int idx = t; idx < OC * CIN * 12 + OC; idx += 256) {
        if (idx < OC * CIN * 12) {
            const int oc = idx / 36, r = idx % 36, c = r / 12, k = r % 12;
            const float f = (k < 9) ? cw[(oc * CIN + c) * 9 + k] : 0.0f;
            const __half h = __float2half_rn(f);
            swb[oc][c][k] = __halves2half2(h, h);
        } else {
            const __half h = __float2half_rn(cb[idx - OC * CIN * 12]);
            sbias[idx - OC * CIN * 12] = __halves2half2(h, h);
        }
    }
    __syncthreads();

    const int bp  = t & 63;         // batch pair within half
    const int ocg = t >> 6;         // 0..3, wave-uniform
    const int j   = blockIdx.x;     // pooled col
    const int i   = blockIdx.y;     // pooled row
    const int bph = blockIdx.z;     // 0..1 batch-pair half
    const int x0  = 2 * j;
    const int yb  = 2 * i;
    const __half2 zero2 = __float2half2_rn(0.0f);

    __half2 acc[4][4];
#pragma unroll
    for (int o = 0; o < 4; ++o)
#pragma unroll
        for (int p = 0; p < 4; ++p) acc[o][p] = zero2;

    const __half2* base = inT2 + bph * 64 + bp;
#pragma unroll
    for (int c = 0; c < CIN; ++c) {
        __half2 V[4][4];
#pragma unroll
        for (int dy = 0; dy < 4; ++dy)
#pragma unroll
            for (int dx = 0; dx < 4; ++dx)
                V[dy][dx] = base[(size_t)((c * HW + yb + dy) * HW + x0 + dx) * 128];

#pragma unroll
        for (int o = 0; o < 4; ++o) {
            const int oc = ocg * 4 + o;
            const float4 w0v = *(const float4*)&swb[oc][c][0];
            const float4 w1v = *(const float4*)&swb[oc][c][4];
            const float4 w2v = *(const float4*)&swb[oc][c][8];
            const __half2* wa = (const __half2*)&w0v;
            const __half2* wb = (const __half2*)&w1v;
            const __half2* wc = (const __half2*)&w2v;
#pragma unroll
            for (int ky = 0; ky < 3; ++ky)
#pragma unroll
                for (int kx = 0; kx < 3; ++kx) {
                    const int n = ky * 3 + kx;           // compile-time after unroll
                    const __half2 w = (n < 4) ? wa[n] : (n < 8) ? wb[n - 4] : wc[n - 8];
                    acc[o][0] = __hfma2(V[ky    ][kx    ], w, acc[o][0]);
                    acc[o][1] = __hfma2(V[ky    ][kx + 1], w, acc[o][1]);
                    acc[o][2] = __hfma2(V[ky + 1][kx    ], w, acc[o][2]);
                    acc[o][3] = __hfma2(V[ky + 1][kx + 1], w, acc[o][3]);
                }
        }
    }

#pragma unroll
    for (int o = 0; o < 4; ++o) {
        const int oc = ocg * 4 + o;
        __half2 m = h2max(h2max(acc[o][0], acc[o][1]), h2max(acc[o][2], acc[o][3]));
        __half2 r = h2max(__hadd2(m, sbias[oc]), zero2);
        featsT2[(size_t)(oc * 3969 + i * POOLED + j) * 128 + bph * 64 + bp] = r;
    }
}

// ---- Kernel 3: sparse hidden layer, half2 gathers ------------------------------
// Grid NH: block = one h. 1024 thr = 8 k-splits x 128 bp lanes (each lane = 2 b).
__global__ __launch_bounds__(1024) void hidden_kernel(const __half2* __restrict__ featsT2,
                                                      const int* __restrict__ hidx,
                                                      const float* __restrict__ hw,
                                                      const float* __restrict__ hb,
                                                      float* __restrict__ hiddenT) {
    __shared__ int    sidx[FANIN];
    __shared__ float  swt[FANIN];
    __shared__ float2 red[1024];
    const int h = blockIdx.x;
    const int t = threadIdx.x;
    if (t < FANIN) {
        sidx[t] = hidx[h * FANIN + t];
        swt[t]  = hw[h * FANIN + t];
    }
    __syncthreads();
    const int bp = t & 127;
    const int ks = t >> 7;          // 0..7
    const int k0 = ks * 64;
    float2 acc; acc.x = 0.f; acc.y = 0.f;
#pragma unroll 16
    for (int kk = 0; kk < 64; ++kk) {
        const int k = k0 + kk;
        const __half2 v = featsT2[(size_t)sidx[k] * 128 + bp];
        const float2 vf = __half22float2(v);
        const float w = swt[k];
        acc.x += vf.x * w;
        acc.y += vf.y * w;
    }
    red[t] = acc;
    __syncthreads();
    if (t < 128) {
        float2 s = red[t];
#pragma unroll
        for (int m = 1; m < 8; ++m) {
            s.x += red[t + 128 * m].x;
            s.y += red[t + 128 * m].y;
        }
        const float bias = hb[h];
        float2 o;
        o.x = 1.0f / (1.0f + __expf(-(s.x + bias)));
        o.y = 1.0f / (1.0f + __expf(-(s.y + bias)));
        *(float2*)&hiddenT[h * BATCH + t * 2] = o;
    }
}

// ---- Kernel 4: dense 256->10 output layer --------------------------------------
__global__ __launch_bounds__(256) void out_kernel(const float* __restrict__ hiddenT,
                                                  const float* __restrict__ ow,
                                                  const float* __restrict__ ob,
                                                  float* __restrict__ out) {
    const int o = blockIdx.x;       // 0..9
    const int b = threadIdx.x;      // 0..255
    float a0 = 0.f, a1 = 0.f, a2 = 0.f, a3 = 0.f;
#pragma unroll 16
    for (int h = 0; h < NH; h += 4) {
        a0 += hiddenT[(h + 0) * BATCH + b] * ow[o * NH + h + 0];
        a1 += hiddenT[(h + 1) * BATCH + b] * ow[o * NH + h + 1];
        a2 += hiddenT[(h + 2) * BATCH + b] * ow[o * NH + h + 2];
        a3 += hiddenT[(h + 3) * BATCH + b] * ow[o * NH + h + 3];
    }
    float acc = (a0 + a1) + (a2 + a3);
    out[b * NO + o] = 1.0f / (1.0f + __expf(-(acc + ob[o])));
}

extern "C" void kernel_launch(void* const* d_in, const int* in_sizes, int n_in,
                              void* d_out, int out_size, void* d_ws, size_t ws_size,
                              hipStream_t stream) {
    const float* inputs   = (const float*)d_in[0];
    const float* conv_w   = (const float*)d_in[1];
    const float* conv_b   = (const float*)d_in[2];
    const int*   hidden_i = (const int*)d_in[3];
    const float* hidden_w = (const float*)d_in[4];
    const float* hidden_b = (const float*)d_in[5];
    const float* out_w    = (const float*)d_in[6];
    const float* out_b    = (const float*)d_in[7];
    float* out = (float*)d_out;

    char* ws = (char*)d_ws;
    __half* inT_h    = (__half*)ws;                                   // 25,165,824 B
    __half* featsT_h = (__half*)(ws + 25165824);                      // 32,514,048 B
    float*  hiddenT  = (float*)(ws + 25165824 + 32514048);            //    262,144 B

    transpose_f16_kernel<<<dim3(CHW / 64, BATCH / 64), 256, 0, stream>>>(inputs, inT_h);
    conv_pool_kernel<<<dim3(POOLED, POOLED, 2), 256, 0, stream>>>((const __half2*)inT_h,
                                                                  conv_w, conv_b,
                                                                  (__half2*)featsT_h);
    hidden_kernel<<<NH, 1024, 0, stream>>>((const __half2*)featsT_h, hidden_i, hidden_w,
                                           hidden_b, hiddenT);
    out_kernel<<<NO, 256, 0, stream>>>(hiddenT, out_w, out_b, out);
}